// Round 1
// baseline (303.371 us; speedup 1.0000x reference)
//
#include <hip/hip_runtime.h>
#include <math.h>

#define S 128
#define H 64

// One block (128 threads, 2 waves) per ray.
// Phase 1: all 128 threads compute the occupancy mask for their sample and
//          compact active sample ids into s_list.
// Phase 2: threads 0..K-1 run the MLP for one active sample each, scatter
//          alpha/rgb back by sample id.
// Phase 3: Hillis-Steele product scan for transmittance, tree reduction for
//          the color sum, white background via total transmittance.
__global__ __launch_bounds__(128)
void raymarch_kernel(const float* __restrict__ rays_o,
                     const float* __restrict__ rays_d,
                     const float* __restrict__ nearv,
                     const float* __restrict__ farv,
                     const float* __restrict__ jitter,
                     const float* __restrict__ density,
                     const float* __restrict__ W1,
                     const float* __restrict__ b1,
                     const float* __restrict__ W2,
                     const float* __restrict__ b2,
                     const float* __restrict__ Wsig,
                     const float* __restrict__ bsig,
                     const float* __restrict__ Wrgb,
                     const float* __restrict__ brgb,
                     float* __restrict__ out)
{
    __shared__ float sW2[H * H];      // 16 KB, [k][j] row-major
    __shared__ float sW1[3 * H];      // [c][h]
    __shared__ float sb1[H];
    __shared__ float sb2[H];
    __shared__ float sWsig[H];
    __shared__ float sWrgb[H * 3];    // [h][c]
    __shared__ float s_alpha[S];
    __shared__ float s_cr[S], s_cg[S], s_cb[S];
    __shared__ float s_scan[S];
    __shared__ int   s_list[S];
    __shared__ int   s_count;
    __shared__ float s_bias4[4];      // bsig, brgb[0..2]

    const int tid = threadIdx.x;
    const int ray = blockIdx.x;

    // ---- stage weights to LDS ----
    for (int i = tid; i < H * H; i += 128) sW2[i] = W2[i];
    for (int i = tid; i < 3 * H; i += 128) { sW1[i] = W1[i]; sWrgb[i] = Wrgb[i]; }
    if (tid < H) { sb1[tid] = b1[tid]; sb2[tid] = b2[tid]; sWsig[tid] = Wsig[tid]; }
    if (tid == 0) {
        s_count = 0;
        s_bias4[0] = bsig[0];
        s_bias4[1] = brgb[0]; s_bias4[2] = brgb[1]; s_bias4[3] = brgb[2];
    }
    s_alpha[tid] = 0.0f;
    s_cr[tid] = 0.0f; s_cg[tid] = 0.0f; s_cb[tid] = 0.0f;
    __syncthreads();

    const float ox = rays_o[ray * 3 + 0], oy = rays_o[ray * 3 + 1], oz = rays_o[ray * 3 + 2];
    const float dx = rays_d[ray * 3 + 0], dy = rays_d[ray * 3 + 1], dz = rays_d[ray * 3 + 2];
    const float nr = nearv[ray];
    const float fr = farv[ray];
    // step = (far - near) / S   (exact: unfused IEEE ops to match numpy)
    const float step = __fdiv_rn(__fsub_rn(fr, nr), 128.0f);

    // ---- phase 1: mask for sample `tid` ----
    // Geometric index path uses _rn intrinsics (no fma contraction): a 1-ulp
    // difference vs numpy can flip a floor() cell and move color ~threshold.
    {
        const float z  = __fadd_rn(nr, __fmul_rn((float)tid, step));
        const float px = __fadd_rn(ox, __fmul_rn(z, dx));
        const float py = __fadd_rn(oy, __fmul_rn(z, dy));
        const float pz = __fadd_rn(oz, __fmul_rn(z, dz));
        const float gx = floorf(__fmul_rn(__fdiv_rn(__fsub_rn(px, -1.25f), 2.5f), 64.0f));
        const float gy = floorf(__fmul_rn(__fdiv_rn(__fsub_rn(py, -1.55f), 2.5f), 64.0f));
        const float gz = floorf(__fmul_rn(__fdiv_rn(__fsub_rn(pz, -1.25f), 2.5f), 64.0f));
        const int ix = (int)gx, iy = (int)gy, iz = (int)gz;
        const bool inb = (ix >= 0) && (ix < 64) && (iy >= 0) && (iy < 64) &&
                         (iz >= 0) && (iz < 64);
        const int cx = min(max(ix, 0), 63);
        const int cy = min(max(iy, 0), 63);
        const int cz = min(max(iz, 0), 63);
        const float dval = density[(cx << 12) | (cy << 6) | cz];
        const bool mask = inb && (dval > 0.5f);   // z > 0 always (near >= 0.05)
        if (mask) {
            const int p = atomicAdd(&s_count, 1);
            s_list[p] = tid;
        }
    }
    __syncthreads();
    const int K = s_count;

    // ---- phase 2: MLP for active samples ----
    if (tid < K) {
        const int s = s_list[tid];
        const float zs = __fadd_rn(nr, __fmul_rn((float)s, step));
        const float zj = zs + jitter[ray * S + s] * step;
        const float qx = ox + zj * dx;
        const float qy = oy + zj * dy;
        const float qz = oz + zj * dz;

        float h2[H];
        #pragma unroll
        for (int j = 0; j < H; ++j) h2[j] = sb2[j];

        #pragma unroll 4
        for (int k = 0; k < H; ++k) {
            // h1_k computed on the fly (used exactly once)
            const float h1k = fmaxf(
                fmaf(qx, sW1[k], fmaf(qy, sW1[H + k], fmaf(qz, sW1[2 * H + k], sb1[k]))),
                0.0f);
            const float* w2row = &sW2[k * H];
            #pragma unroll
            for (int j = 0; j < H; ++j) h2[j] = fmaf(h1k, w2row[j], h2[j]);
        }

        float sig = s_bias4[0];
        float r = s_bias4[1], g = s_bias4[2], b = s_bias4[3];
        #pragma unroll
        for (int j = 0; j < H; ++j) {
            const float v = fmaxf(h2[j], 0.0f);
            sig = fmaf(v, sWsig[j], sig);
            r = fmaf(v, sWrgb[j * 3 + 0], r);
            g = fmaf(v, sWrgb[j * 3 + 1], g);
            b = fmaf(v, sWrgb[j * 3 + 2], b);
        }
        const float tau = fmaxf(sig, 0.0f) * step;
        const float alpha = 1.0f - expf(-tau);
        r = 1.0f / (1.0f + expf(-r));
        g = 1.0f / (1.0f + expf(-g));
        b = 1.0f / (1.0f + expf(-b));
        s_alpha[s] = alpha;
        s_cr[s] = r; s_cg[s] = g; s_cb[s] = b;
    }
    __syncthreads();

    // ---- phase 3: composite ----
    // term = (1 - alpha) + 1e-10 (the 1e-10 underflows ulp(1.0) in fp32 for
    // alpha=0 — identical to the fp32 reference)
    const float term = (1.0f - s_alpha[tid]) + 1e-10f;
    s_scan[tid] = term;
    __syncthreads();
    #pragma unroll
    for (int off = 1; off < S; off <<= 1) {
        const float vs = s_scan[tid];
        const float vp = (tid >= off) ? s_scan[tid - off] : 1.0f;
        __syncthreads();
        s_scan[tid] = vs * vp;
        __syncthreads();
    }
    const float trans_ex = (tid == 0) ? 1.0f : s_scan[tid - 1];
    const float no_hit = s_scan[S - 1];
    const float w = s_alpha[tid] * trans_ex;
    const float cr = w * s_cr[tid];
    const float cg = w * s_cg[tid];
    const float cb = w * s_cb[tid];
    __syncthreads();
    s_cr[tid] = cr; s_cg[tid] = cg; s_cb[tid] = cb;
    __syncthreads();
    #pragma unroll
    for (int off = 64; off > 0; off >>= 1) {
        if (tid < off) {
            s_cr[tid] += s_cr[tid + off];
            s_cg[tid] += s_cg[tid + off];
            s_cb[tid] += s_cb[tid + off];
        }
        __syncthreads();
    }
    if (tid == 0) {
        out[ray * 3 + 0] = s_cr[0] + no_hit;
        out[ray * 3 + 1] = s_cg[0] + no_hit;
        out[ray * 3 + 2] = s_cb[0] + no_hit;
    }
}

extern "C" void kernel_launch(void* const* d_in, const int* in_sizes, int n_in,
                              void* d_out, int out_size, void* d_ws, size_t ws_size,
                              hipStream_t stream) {
    const float* rays_o  = (const float*)d_in[0];
    const float* rays_d  = (const float*)d_in[1];
    const float* nearv   = (const float*)d_in[2];
    const float* farv    = (const float*)d_in[3];
    const float* jitter  = (const float*)d_in[4];
    const float* density = (const float*)d_in[5];
    const float* W1      = (const float*)d_in[6];
    const float* b1      = (const float*)d_in[7];
    const float* W2      = (const float*)d_in[8];
    const float* b2      = (const float*)d_in[9];
    const float* Wsig    = (const float*)d_in[10];
    const float* bsig    = (const float*)d_in[11];
    const float* Wrgb    = (const float*)d_in[12];
    const float* brgb    = (const float*)d_in[13];
    float* out = (float*)d_out;

    const int N = in_sizes[2];   // number of rays (near has one entry per ray)

    raymarch_kernel<<<dim3(N), dim3(128), 0, stream>>>(
        rays_o, rays_d, nearv, farv, jitter, density,
        W1, b1, W2, b2, Wsig, bsig, Wrgb, brgb, out);
}